// Round 11
// baseline (163.210 us; speedup 1.0000x reference)
//
#include <hip/hip_runtime.h>

// PNN / RBF classifier, MI355X. Round 11: PERSISTENT-BLOCK fp8 packed GEMM.
// Cross-round evidence (r7->r8: dur ~ #blocks at const work; occupancy 11-15%;
// fp4 halving all pipe terms changed nothing) says the ~37us wall is per-block
// cost / CU starvation, not the inner loop. Now: 256 blocks = 1/CU, each owns
// a 128q x 1024t strip = 4 sequential r9-tiles -> per-block cost amortized 4x,
// waves resident the whole kernel. Inner structure = r9 verbatim (proven):
// packed fragment-major fp8, LDS dbuf, dense lane*16 (0 conflicts, no swizzle),
// vmcnt(3) counted prefetch, 2 barriers/K-step. setprio dropped (m190).
// dist2(q,t) = xx[q]+tt[t]-2*dot. exp(-dist2/8) underflows fp32-normal unless
// dist2 < 698.69 (FTZ matches XLA ref; verified r1-r10, absmax=0). fp8 MFMA
// screens at 730; flagged pairs recomputed exactly in fp32 from global.
// Nothing enters classacc unconfirmed -> correctness by construction.
//
// Packed layout (verified r8/r9): chunk(rt,kt)=2048B at (rt*8+kt)*2048; lane
// slot l=(row&31)+32*k32half at l*16 (+1024 for 16B-half h=1). MFMA lane l
// reads [l*16,+16) and [1024+l*16,+16) -> exactly its 32x32x64 fp8 operand.

#define NQ 4096
#define NT 8192
#define DD 512
#define NC 16
#define LN_FLT_MIN -87.336544750402f
#define SCREEN_T 730.0f

typedef __attribute__((ext_vector_type(4))) int   v4i;
typedef __attribute__((ext_vector_type(8))) int   v8i;
typedef __attribute__((ext_vector_type(16))) float f32x16;

__global__ __launch_bounds__(256) void prep_k(const float* __restrict__ X,
                                              const float* __restrict__ XT,
                                              unsigned char* __restrict__ fXp,
                                              unsigned char* __restrict__ fTp,
                                              float* __restrict__ xx,
                                              float* __restrict__ tt,
                                              float* __restrict__ classacc) {
  const int lane = threadIdx.x & 63;
  const int row  = blockIdx.x * 4 + (threadIdx.x >> 6);
  const float* src; unsigned char* dst; float* nrm; int r;
  if (row < NT) { r = row; src = XT + (size_t)r * DD; dst = fTp; nrm = tt + r; }
  else { r = row - NT; src = X + (size_t)r * DD; dst = fXp; nrm = xx + r; }
  const float4* s4 = (const float4*)src;
  const float4 a = s4[lane * 2], b = s4[lane * 2 + 1];   // k-bytes lane*8 .. +7
  int w0 = __builtin_amdgcn_cvt_pk_fp8_f32(a.x, a.y, 0, false);
  w0     = __builtin_amdgcn_cvt_pk_fp8_f32(a.z, a.w, w0, true);
  int w1 = __builtin_amdgcn_cvt_pk_fp8_f32(b.x, b.y, 0, false);
  w1     = __builtin_amdgcn_cvt_pk_fp8_f32(b.z, b.w, w1, true);
  int2 o; o.x = w0; o.y = w1;
  const int l = (r & 31) + 32 * ((lane >> 2) & 1);
  const size_t dest = ((size_t)(r >> 5) * 8 + (lane >> 3)) * 2048
                    + ((lane >> 1) & 1) * 1024 + l * 16 + (lane & 1) * 8;
  *(int2*)(dst + dest) = o;
  float acc = a.x*a.x + a.y*a.y + a.z*a.z + a.w*a.w
            + b.x*b.x + b.y*b.y + b.z*b.z + b.w*b.w;
  #pragma unroll
  for (int off = 32; off; off >>= 1) acc += __shfl_down(acc, off, 64);
  if (lane == 0) *nrm = acc;
  if (blockIdx.x < 64) {
    float4 z = {0.f, 0.f, 0.f, 0.f};
    ((float4*)classacc)[blockIdx.x * 256 + threadIdx.x] = z;
  }
}

#define MFMA(A, B, C) __builtin_amdgcn_mfma_scale_f32_32x32x64_f8f6f4( \
    (A), (B), (C), 0, 0, 0, 127, 0, 127)
#define BAR() __builtin_amdgcn_s_barrier()
#define WAITV(N) asm volatile("s_waitcnt vmcnt(" #N ")" ::: "memory")

static __device__ __forceinline__ void gll(const unsigned char* src, char* dst) {
  __builtin_amdgcn_global_load_lds(
      (const __attribute__((address_space(1))) unsigned int*)src,
      (__attribute__((address_space(3))) unsigned int*)dst, 16, 0, 0);
}

static __device__ __forceinline__ v8i ld32(const char* p) {
  v4i lo = *(const v4i*)p;            // lanes dense: lane*16 -> no bank conflict
  v4i hi = *(const v4i*)(p + 1024);
  return __builtin_shufflevector(lo, hi, 0, 1, 2, 3, 4, 5, 6, 7);
}

__global__ __launch_bounds__(512) void pnn_mfma(const unsigned char* __restrict__ fXp,
                                                const unsigned char* __restrict__ fTp,
                                                const float* __restrict__ Xf,
                                                const float* __restrict__ Tf,
                                                const int* __restrict__ y,
                                                const float* __restrict__ sigp,
                                                const float* __restrict__ xx,
                                                const float* __restrict__ tt,
                                                float* __restrict__ classacc) {
  __shared__ char lds[49152];   // A0|A1 (8K each) | B0|B1 (16K each)
  const int tid  = threadIdx.x;
  const int wid  = tid >> 6, lane = tid & 63;
  const int la   = lane & 31, lb = lane >> 5;
  const int wr   = wid >> 2, wc = wid & 3;    // 2M x 4N waves, 64x64 tile each

  // persistent map: 256 blocks = 32 qt x 8 strips; strip = XCD (bid&7):
  // per-XCD L2 set = B strip 512 KB (shared by its 32 blocks) + A 2 MB.
  const int bid   = blockIdx.x;
  const int strip = bid & 7;
  const int qt    = bid >> 3;                 // 0..31
  const int qbase = qt * 128;
  const int qrt0  = qbase >> 5;

  char* const A0 = lds;
  char* const A1 = lds + 8192;
  char* const B0 = lds + 16384;
  char* const B1 = lds + 32768;

  const int sc = tid >> 7;                    // staging chunk 0..3
  const int si = (tid & 127) * 16;            // staging inner byte

  const float sg = sigp[0];
  const float inv2s2 = 1.0f / (2.0f * sg * sg);
  const int wq = qbase + wr * 64;

  for (int tile = 0; tile < 4; ++tile) {
    const int tbase = strip * 1024 + tile * 256;
    const int trt0  = tbase >> 5;

#define STAGE(kt, Ab, Bb) { \
    gll(fXp + ((size_t)(qrt0 + sc) * 8 + (kt)) * 2048 + si, (Ab) + sc * 2048 + si); \
    gll(fTp + ((size_t)(trt0 + sc) * 8 + (kt)) * 2048 + si, (Bb) + sc * 2048 + si); \
    gll(fTp + ((size_t)(trt0 + sc + 4) * 8 + (kt)) * 2048 + si, (Bb) + (sc + 4) * 2048 + si); }

    f32x16 acc00 = (f32x16)(0.f), acc01 = (f32x16)(0.f);
    f32x16 acc10 = (f32x16)(0.f), acc11 = (f32x16)(0.f);

    STAGE(0, A0, B0)                          // tile prologue

    #pragma unroll
    for (int kt = 0; kt < 8; ++kt) {          // unrolled: kt static
      char* const Ac = (kt & 1) ? A1 : A0;
      char* const Bc = (kt & 1) ? B1 : B0;
      char* const An = (kt & 1) ? A0 : A1;
      char* const Bn = (kt & 1) ? B0 : B1;
      if (kt < 7) { STAGE(kt + 1, An, Bn) }   // issue next (latency spans iter)
      if (kt < 7) { WAITV(3); } else { WAITV(0); }  // own stage(kt) landed
      BAR();                                  // all waves' stage(kt) landed
      const v8i a0 = ld32(Ac + (wr * 2 + 0) * 2048 + lane * 16);
      const v8i a1 = ld32(Ac + (wr * 2 + 1) * 2048 + lane * 16);
      const v8i b0 = ld32(Bc + (wc * 2 + 0) * 2048 + lane * 16);
      const v8i b1 = ld32(Bc + (wc * 2 + 1) * 2048 + lane * 16);
      acc00 = MFMA(a0, b0, acc00);
      acc01 = MFMA(a0, b1, acc01);
      acc10 = MFMA(a1, b0, acc10);
      acc11 = MFMA(a1, b1, acc11);
      if (kt < 7) BAR();                      // reads done before buf overwrite
    }
#undef STAGE

    // epilogue: screen + (rare) exact fp32 path -> global class atomics.
    // C/D 32x32 map: col = la, row = (reg&3) + 8*(reg>>2) + 4*lb  [m74/m101]
    const int wt = tbase + wc * 64;
    float tnorm[2]; int tcls[2];
    #pragma unroll
    for (int nt = 0; nt < 2; ++nt) {
      const int t = wt + nt * 32 + la;
      tnorm[nt] = tt[t]; tcls[nt] = y[t];
    }

#define EPIL(ACC, mt, nt) { \
    _Pragma("unroll") \
    for (int reg = 0; reg < 16; ++reg) { \
      const int q = wq + (mt) * 32 + (reg & 3) + 8 * (reg >> 2) + 4 * lb; \
      const float xq = xx[q]; \
      const float d2 = xq + tnorm[(nt)] - 2.0f * (ACC)[reg]; \
      if (__builtin_expect(d2 < SCREEN_T, 0)) { \
        const int t = wt + (nt) * 32 + la; \
        const float4* xp = (const float4*)(Xf + (size_t)q * DD); \
        const float4* tp = (const float4*)(Tf + (size_t)t * DD); \
        float s0 = 0.f, s1 = 0.f, s2 = 0.f, s3 = 0.f; \
        for (int d = 0; d < DD / 4; ++d) { \
          const float4 xv = xp[d], tv = tp[d]; \
          s0 = fmaf(xv.x, tv.x, s0); s1 = fmaf(xv.y, tv.y, s1); \
          s2 = fmaf(xv.z, tv.z, s2); s3 = fmaf(xv.w, tv.w, s3); \
        } \
        const float dot = (s0 + s1) + (s2 + s3); \
        const float dd2 = fmaxf(xq + tnorm[(nt)] - 2.0f * dot, 0.f); \
        const float arg = -dd2 * inv2s2; \
        if (arg >= LN_FLT_MIN)            /* below: fp32 exp subnormal -> FTZ 0 */ \
          atomicAdd(&classacc[q * NC + tcls[(nt)]], expf(arg)); \
      } \
    } }

    EPIL(acc00, 0, 0)
    EPIL(acc01, 0, 1)
    EPIL(acc10, 1, 0)
    EPIL(acc11, 1, 1)
#undef EPIL

    WAITV(0);                 // epilogue vmem (incl. rare atomics) drained:
    BAR();                    // clean vmcnt ledger + WAR guard for next tile
  }
}

__global__ __launch_bounds__(256) void argmax_k(const float* __restrict__ classacc,
                                                float* __restrict__ out) {
  const int q = blockIdx.x * 256 + threadIdx.x;
  float sc[NC];
  #pragma unroll
  for (int c4 = 0; c4 < 4; ++c4) {
    const float4 v = ((const float4*)(classacc + (size_t)q * NC))[c4];
    sc[c4*4+0] = v.x; sc[c4*4+1] = v.y; sc[c4*4+2] = v.z; sc[c4*4+3] = v.w;
  }
  float rowsum = 0.f;
  #pragma unroll
  for (int c = 0; c < NC; ++c) rowsum += sc[c];
  int best = 0; float bv = sc[0];
  #pragma unroll
  for (int c = 1; c < NC; ++c)
    if (sc[c] > bv) { bv = sc[c]; best = c; }   // strict > = first max (jnp.argmax)
  out[q] = (rowsum > 0.f) ? (float)best : 0.0f; // all-zero row -> NaN in ref -> 0
}

extern "C" void kernel_launch(void* const* d_in, const int* in_sizes, int n_in,
                              void* d_out, int out_size, void* d_ws, size_t ws_size,
                              hipStream_t stream) {
  const float* X  = (const float*)d_in[0];
  const float* XT = (const float*)d_in[1];
  const int*   y  = (const int*)d_in[2];
  const float* sg = (const float*)d_in[3];
  float* out = (float*)d_out;

  char* wsp = (char*)d_ws;
  unsigned char* fXp = (unsigned char*)wsp;                        // 2 MB packed
  unsigned char* fTp = fXp + (size_t)NQ * DD;                      // 4 MB packed
  float* tt       = (float*)(wsp + 8u * 1024u * 1024u);            // NT f32
  float* xx       = tt + NT;                                       // NQ f32
  float* classacc = xx + NQ;                                       // 256 KB

  prep_k<<<(NQ + NT) / 4, 256, 0, stream>>>(X, XT, fXp, fTp, xx, tt, classacc);
  pnn_mfma<<<256, 512, 0, stream>>>(fXp, fTp, X, XT, y, sg, xx, tt, classacc);
  argmax_k<<<NQ / 256, 256, 0, stream>>>(classacc, out);
}

// Round 12
// 45.321 us; speedup vs baseline: 3.6012x; 3.6012x over previous
//
#include <hip/hip_runtime.h>

// PNN / RBF classifier, MI355X. Round 12: single-round-trip MX-fp4 GEMM.
// Theory: the ~40us wall across r4-r10 is 8-32 SEQUENTIAL dependent
// global->compute round-trips per block under queue-amplified L2 latency.
// This kernel collapses to ~1 round-trip: A panel (128q x 512k fp4) lives in
// REGISTERS (16 v4i/lane/wave), B tile (256t x 512k fp4 = 64 KB) is staged
// whole into LDS (double-buffered 128 KB); 256 persistent blocks (1/CU) each
// compute 4 sequential 128x256 tiles. Tile loop unroll(disable) + (512,1)
// launch bounds to avoid r6/r11 spill disasters.
// dist2(q,t) = xx[q]+tt[t]-2*dot. exp(-dist2/8) underflows fp32-normal unless
// dist2 < 698.69 (FTZ matches XLA ref; verified r1-r11, absmax=0). fp4 GEMM
// is only a SCREEN (threshold 750, ~6.4 sigma margin); flagged pairs are
// recomputed exactly in fp32 from global. Nothing enters classacc unconfirmed.
//
// fp4 packed layout (r10-verified): chunk(rt,kt) = 1024 B at (rt*8+kt)*1024;
// rt = row>>5, kt = k>>6. Lane slot l = (row&31) + 32*((k>>5)&1) holds its
// 32 k-elems (16 B) at l*16. MFMA lane reads exactly [l*16, +16).

#define NQ 4096
#define NT 8192
#define DD 512
#define NC 16
#define LN_FLT_MIN -87.336544750402f
#define SCREEN_T 750.0f

typedef __attribute__((ext_vector_type(4))) int   v4i;
typedef __attribute__((ext_vector_type(8))) int   v8i;
typedef __attribute__((ext_vector_type(16))) float f32x16;

static __device__ __forceinline__ unsigned f2fp4(float x) {
  // e2m1 RTNE via thresholds; levels 0,.5,1,1.5,2,3,4,6 (sat at 6)
  const float a = __builtin_fabsf(x);
  unsigned i = (unsigned)(a >= 0.25f) + (a >= 0.75f) + (a >= 1.25f)
             + (a >= 1.75f) + (a >= 2.5f) + (a >= 3.5f) + (a >= 5.0f);
  return i | (x < 0.0f ? 8u : 0u);
}

__global__ __launch_bounds__(256) void prep_k(const float* __restrict__ X,
                                              const float* __restrict__ XT,
                                              unsigned char* __restrict__ fXp,
                                              unsigned char* __restrict__ fTp,
                                              float* __restrict__ xx,
                                              float* __restrict__ tt,
                                              float* __restrict__ classacc) {
  const int lane = threadIdx.x & 63;
  const int row  = blockIdx.x * 4 + (threadIdx.x >> 6);
  const float* src; unsigned char* dst; float* nrm; int r;
  if (row < NT) { r = row; src = XT + (size_t)r * DD; dst = fTp; nrm = tt + r; }
  else { r = row - NT; src = X + (size_t)r * DD; dst = fXp; nrm = xx + r; }
  const float4* s4 = (const float4*)src;
  const float4 a = s4[lane * 2], b = s4[lane * 2 + 1];   // k = lane*8 .. +7
  const unsigned word =  f2fp4(a.x)        | (f2fp4(a.y) << 4)
                      | (f2fp4(a.z) << 8)  | (f2fp4(a.w) << 12)
                      | (f2fp4(b.x) << 16) | (f2fp4(b.y) << 20)
                      | (f2fp4(b.z) << 24) | (f2fp4(b.w) << 28);
  const int l = (r & 31) + 32 * ((lane >> 2) & 1);
  const size_t dest = ((size_t)(r >> 5) * 8 + (lane >> 3)) * 1024
                    + l * 16 + (lane & 3) * 4;
  *(unsigned*)(dst + dest) = word;
  float acc = a.x*a.x + a.y*a.y + a.z*a.z + a.w*a.w
            + b.x*b.x + b.y*b.y + b.z*b.z + b.w*b.w;
  #pragma unroll
  for (int off = 32; off; off >>= 1) acc += __shfl_down(acc, off, 64);
  if (lane == 0) *nrm = acc;
  if (blockIdx.x < 64) {
    float4 z = {0.f, 0.f, 0.f, 0.f};
    ((float4*)classacc)[blockIdx.x * 256 + threadIdx.x] = z;
  }
}

#define MFMA4(A, B, C) __builtin_amdgcn_mfma_scale_f32_32x32x64_f8f6f4( \
    (A), (B), (C), 4, 4, 0, 127, 0, 127)   // fmt 4 = FP4 e2m1; 127 = x1.0
#define BAR() __builtin_amdgcn_s_barrier()
#define WAITV0() asm volatile("s_waitcnt vmcnt(0)" ::: "memory")

static __device__ __forceinline__ void gll(const unsigned char* src, char* dst) {
  __builtin_amdgcn_global_load_lds(
      (const __attribute__((address_space(1))) unsigned int*)src,
      (__attribute__((address_space(3))) unsigned int*)dst, 16, 0, 0);
}

static __device__ __forceinline__ v8i pk8(v4i lo) {
  return __builtin_shufflevector(lo, lo, 0, 1, 2, 3, -1, -1, -1, -1); // fp4 uses v[0:3]
}

__global__ __launch_bounds__(512, 1) void pnn_mfma(const unsigned char* __restrict__ fXp,
                                                   const unsigned char* __restrict__ fTp,
                                                   const float* __restrict__ Xf,
                                                   const float* __restrict__ Tf,
                                                   const int* __restrict__ y,
                                                   const float* __restrict__ sigp,
                                                   const float* __restrict__ xx,
                                                   const float* __restrict__ tt,
                                                   float* __restrict__ classacc) {
  extern __shared__ char lds[];               // B0 | B1, 64 KB each
  const int tid  = threadIdx.x;
  const int w    = tid >> 6, lane = tid & 63;
  const int la   = lane & 31, lb = lane >> 5;
  const int wr   = w >> 2, wc = w & 3;        // 2M x 4N waves, 64x64 tiles

  // persistent: 256 blocks = 32 qt x 8 strips (strip = bid&7 ~ XCD);
  // each block: 128 q-rows x (strip's 1024 t-cols as 4 tiles of 256).
  const int bid   = blockIdx.x;
  const int strip = bid & 7;
  const int qt    = bid >> 3;
  const int qbase = qt * 128;
  const int rt0   = (qbase >> 5) + wr * 2;    // wave's A row-tiles

  const float sg = sigp[0];
  const float inv2s2 = 1.0f / (2.0f * sg * sg);
  const int wq = qbase + wr * 64;

  // ---- A panel -> registers: 16 v4i (64 VGPR), one burst ----
  v4i av[2][8];
  #pragma unroll
  for (int mt = 0; mt < 2; ++mt)
    #pragma unroll
    for (int kt = 0; kt < 8; ++kt)
      av[mt][kt] = *(const v4i*)(fXp + ((size_t)(rt0 + mt) * 8 + kt) * 1024 + lane * 16);

  // ---- B staging: whole 256x512 tile (64 chunks x 1 KB); wave w stages
  // kt=w chunks of row-tiles j=0..7; LDS chunk index c = j*8 + w ----
#define STAGEB(buf, trt0) { \
    _Pragma("unroll") \
    for (int j = 0; j < 8; ++j) \
      gll(fTp + ((size_t)((trt0) + j) * 8 + w) * 1024 + lane * 16, \
          (buf) + (j * 8 + w) * 1024 + lane * 16); }

  char* cur = lds;
  char* nxt = lds + 65536;

  STAGEB(cur, strip * 32)                     // tile 0
  WAITV0();                                    // A regs + B0 landed (1 round-trip)
  BAR();

  #pragma clang loop unroll(disable)
  for (int t = 0; t < 4; ++t) {
    if (t < 3) STAGEB(nxt, strip * 32 + (t + 1) * 8)   // hidden under compute

    f32x16 acc00 = (f32x16)(0.f), acc01 = (f32x16)(0.f);
    f32x16 acc10 = (f32x16)(0.f), acc11 = (f32x16)(0.f);

    #pragma unroll
    for (int kt = 0; kt < 8; ++kt) {          // all from regs + LDS: no global dep
      const v4i b0 = *(const v4i*)(cur + ((wc * 2 + 0) * 8 + kt) * 1024 + lane * 16);
      const v4i b1 = *(const v4i*)(cur + ((wc * 2 + 1) * 8 + kt) * 1024 + lane * 16);
      const v8i a0 = pk8(av[0][kt]), a1 = pk8(av[1][kt]);
      const v8i bb0 = pk8(b0), bb1 = pk8(b1);
      acc00 = MFMA4(a0, bb0, acc00);
      acc01 = MFMA4(a0, bb1, acc01);
      acc10 = MFMA4(a1, bb0, acc10);
      acc11 = MFMA4(a1, bb1, acc11);
    }

    // epilogue: screen + (rare) exact fp32 path -> global class atomics.
    // C/D 32x32 map: col = la, row = (reg&3) + 8*(reg>>2) + 4*lb  [m74/m101]
    const int tbase = strip * 1024 + t * 256;
    const int wt = tbase + wc * 64;
    float tnorm[2]; int tcls[2];
    #pragma unroll
    for (int nt = 0; nt < 2; ++nt) {
      const int tg = wt + nt * 32 + la;
      tnorm[nt] = tt[tg]; tcls[nt] = y[tg];
    }

#define EPIL(ACC, mt, nt) { \
    _Pragma("unroll") \
    for (int reg = 0; reg < 16; ++reg) { \
      const int q = wq + (mt) * 32 + (reg & 3) + 8 * (reg >> 2) + 4 * lb; \
      const float xq = xx[q]; \
      const float d2 = xq + tnorm[(nt)] - 2.0f * (ACC)[reg]; \
      if (__builtin_expect(d2 < SCREEN_T, 0)) { \
        const int tg = wt + (nt) * 32 + la; \
        const float4* xp = (const float4*)(Xf + (size_t)q * DD); \
        const float4* tp = (const float4*)(Tf + (size_t)tg * DD); \
        float s0 = 0.f, s1 = 0.f, s2 = 0.f, s3 = 0.f; \
        for (int d = 0; d < DD / 4; ++d) { \
          const float4 xv = xp[d], tv = tp[d]; \
          s0 = fmaf(xv.x, tv.x, s0); s1 = fmaf(xv.y, tv.y, s1); \
          s2 = fmaf(xv.z, tv.z, s2); s3 = fmaf(xv.w, tv.w, s3); \
        } \
        const float dot = (s0 + s1) + (s2 + s3); \
        const float dd2 = fmaxf(xq + tnorm[(nt)] - 2.0f * dot, 0.f); \
        const float arg = -dd2 * inv2s2; \
        if (arg >= LN_FLT_MIN)            /* below: fp32 exp subnormal -> FTZ 0 */ \
          atomicAdd(&classacc[q * NC + tcls[(nt)]], expf(arg)); \
      } \
    } }

    EPIL(acc00, 0, 0)
    EPIL(acc01, 0, 1)
    EPIL(acc10, 1, 0)
    EPIL(acc11, 1, 1)
#undef EPIL

    WAITV0();                 // B(t+1) + epilogue vmem drained
    BAR();                    // WAR guard: cur free to overwrite next iter
    char* tmp = cur; cur = nxt; nxt = tmp;
  }
#undef STAGEB
}

__global__ __launch_bounds__(256) void argmax_k(const float* __restrict__ classacc,
                                                float* __restrict__ out) {
  const int q = blockIdx.x * 256 + threadIdx.x;
  float sc[NC];
  #pragma unroll
  for (int c4 = 0; c4 < 4; ++c4) {
    const float4 v = ((const float4*)(classacc + (size_t)q * NC))[c4];
    sc[c4*4+0] = v.x; sc[c4*4+1] = v.y; sc[c4*4+2] = v.z; sc[c4*4+3] = v.w;
  }
  float rowsum = 0.f;
  #pragma unroll
  for (int c = 0; c < NC; ++c) rowsum += sc[c];
  int best = 0; float bv = sc[0];
  #pragma unroll
  for (int c = 1; c < NC; ++c)
    if (sc[c] > bv) { bv = sc[c]; best = c; }   // strict > = first max (jnp.argmax)
  out[q] = (rowsum > 0.f) ? (float)best : 0.0f; // all-zero row -> NaN in ref -> 0
}

extern "C" void kernel_launch(void* const* d_in, const int* in_sizes, int n_in,
                              void* d_out, int out_size, void* d_ws, size_t ws_size,
                              hipStream_t stream) {
  const float* X  = (const float*)d_in[0];
  const float* XT = (const float*)d_in[1];
  const int*   y  = (const int*)d_in[2];
  const float* sg = (const float*)d_in[3];
  float* out = (float*)d_out;

  char* wsp = (char*)d_ws;
  unsigned char* fXp = (unsigned char*)wsp;                        // 1 MB fp4 packed
  unsigned char* fTp = fXp + (size_t)NQ * DD / 2;                  // 2 MB fp4 packed
  float* tt       = (float*)(wsp + 4u * 1024u * 1024u);            // NT f32
  float* xx       = tt + NT;                                       // NQ f32
  float* classacc = xx + NQ;                                       // 256 KB

  (void)hipFuncSetAttribute((const void*)pnn_mfma,
                            hipFuncAttributeMaxDynamicSharedMemorySize, 131072);

  prep_k<<<(NQ + NT) / 4, 256, 0, stream>>>(X, XT, fXp, fTp, xx, tt, classacc);
  pnn_mfma<<<256, 512, 131072, stream>>>(fXp, fTp, X, XT, y, sg, xx, tt, classacc);
  argmax_k<<<NQ / 256, 256, 0, stream>>>(classacc, out);
}